// Round 7
// baseline (291.141 us; speedup 1.0000x reference)
//
#include <hip/hip_runtime.h>

#define LOG2E 1.44269504088896340736f

typedef _Float16 f16;
typedef __attribute__((ext_vector_type(2))) _Float16 f16x2;
typedef __attribute__((ext_vector_type(2))) __fp16 fp16x2;
typedef __attribute__((ext_vector_type(4))) _Float16 f16x4;
typedef __attribute__((ext_vector_type(8))) _Float16 f16x8;
typedef __attribute__((ext_vector_type(4))) float f32x4;
typedef __attribute__((ext_vector_type(16))) float f32x16;
typedef __attribute__((ext_vector_type(8))) unsigned short us8;
typedef __attribute__((ext_vector_type(2))) int i32x2;

#define BB 32
#define SSX 2048
#define SSY 2048
#define DD 160
#define M_TOTAL (BB*SSX)   // 65536

#define PRS 168    // proj epilogue row stride (f16)
#define VTRS 136   // proj V^T store buffer stride
#define RS 168     // flash K/Q LDS stride (pad-8: const-offset ds_reads)

__device__ __forceinline__ f32x4 mfma16(f16x8 a, f16x8 b, f32x4 c) {
  return __builtin_amdgcn_mfma_f32_16x16x32_f16(a, b, c, 0, 0, 0);
}

__device__ __forceinline__ f32x16 mfma32(f16x8 a, f16x8 b, f32x16 c) {
  return __builtin_amdgcn_mfma_f32_32x32x16_f16(a, b, c, 0, 0, 0);
}

// RTZ pack of two f32 -> u32 of 2 f16 (low = a). P in [0,1]: RTZ error ~2^-12, negligible.
__device__ __forceinline__ unsigned pk2rtz(float a, float b) {
  union { fp16x2 h; unsigned u; } x;
  x.h = __builtin_amdgcn_cvt_pkrtz(a, b);
  return x.u;
}

// ---- W pre-conversion: fp32 -> f16 once ----
__global__ __launch_bounds__(256) void wcvt_kernel(
    const float* __restrict__ Wq, const float* __restrict__ Wk, const float* __restrict__ Wv,
    f16* __restrict__ Wf)
{
  int idx = blockIdx.x*256 + threadIdx.x;   // 75 blocks * 256 = 19200 float4
  int which = idx / 6400;                   // uniform per block (6400 % 256 == 0)
  int off   = idx % 6400;
  const float* src = (which == 0) ? Wq : (which == 1 ? Wk : Wv);
  float4 v = *(const float4*)&src[off*4];
  f16x4 h = { (f16)v.x, (f16)v.y, (f16)v.z, (f16)v.w };
  *(f16x4*)&Wf[which*25600 + off*4] = h;
}

// ---- Projection v4: all operands DIRECT to registers (no input/W LDS staging,
// no mid-kernel barriers). Input rows are wave-partitioned (zero cross-wave reuse
// -> staging was pure overhead); A-frag quads tile 128-B lines, B-frags hit L2.
// LDS used only for the output-transpose epilogue. 1536 uniform blocks.
__global__ __launch_bounds__(256, 3) void proj_kernel(
    const float* __restrict__ x, const float* __restrict__ y,
    const float* __restrict__ bq, const float* __restrict__ bk, const float* __restrict__ bv,
    const f16* __restrict__ Wf,
    f16* __restrict__ Qw, f16* __restrict__ Kw, f16* __restrict__ Vtw)
{
  __shared__ __align__(16) f16 buf[160*VTRS];   // 43520 B (also used as 128 x PRS = 43008)
  const int t = threadIdx.x;
  const int wave = t >> 6;
  const int lane = t & 63;
  const int quad = lane >> 4;
  const int l16  = lane & 15;
  // 1536 blocks = 8 XCDs x 192: contiguous logical range per XCD; K,V adjacent share y-tile in L2
  const int bid  = (blockIdx.x & 7) * 192 + (blockIdx.x >> 3);
  const int kind = bid % 3;          // 0=Q, 1=K, 2=V
  const int tile = bid / 3;
  const int row0 = tile * 128;
  const float* src  = (kind == 0) ? x  : y;
  const f16*   W    = Wf + kind*25600;
  const float* bias = (kind == 0) ? bq : (kind == 1 ? bk : bv);

  // A-fragments: global f32 -> f16 registers
  f16x8 afr0[5], afr1[5];
  {
    const float* r0p = src + (size_t)(row0 + wave*32 + l16)*DD;
    const float* r1p = r0p + 16*DD;
    #pragma unroll
    for (int ks = 0; ks < 5; ++ks) {
      float4 a = *(const float4*)&r0p[ks*32 + quad*8];
      float4 b = *(const float4*)&r0p[ks*32 + quad*8 + 4];
      afr0[ks] = (f16x8){(f16)a.x,(f16)a.y,(f16)a.z,(f16)a.w,
                         (f16)b.x,(f16)b.y,(f16)b.z,(f16)b.w};
      float4 c = *(const float4*)&r1p[ks*32 + quad*8];
      float4 d = *(const float4*)&r1p[ks*32 + quad*8 + 4];
      afr1[ks] = (f16x8){(f16)c.x,(f16)c.y,(f16)c.z,(f16)c.w,
                         (f16)d.x,(f16)d.y,(f16)d.z,(f16)d.w};
    }
  }

  // MFMA: B-fragments direct from L2-resident f16 W
  f32x4 acc0[10], acc1[10];
  #pragma unroll
  for (int nt = 0; nt < 10; ++nt) {
    float bs = bias[nt*16 + l16];
    acc0[nt] = (f32x4){bs,bs,bs,bs};
    acc1[nt] = (f32x4){bs,bs,bs,bs};
    #pragma unroll
    for (int ks = 0; ks < 5; ++ks) {
      f16x8 bfr = *(const f16x8*)&W[(nt*16 + l16)*160 + ks*32 + quad*8];
      acc0[nt] = mfma16(afr0[ks], bfr, acc0[nt]);
      acc1[nt] = mfma16(afr1[ks], bfr, acc1[nt]);
    }
  }

  if (kind < 2) {
    f16* dst = (kind == 0) ? Qw : Kw;
    #pragma unroll
    for (int nt = 0; nt < 10; ++nt)
      #pragma unroll
      for (int r = 0; r < 4; ++r) {
        buf[(wave*32 + quad*4 + r)*PRS + nt*16 + l16]      = (f16)acc0[nt][r];
        buf[(wave*32 + 16 + quad*4 + r)*PRS + nt*16 + l16] = (f16)acc1[nt][r];
      }
    __syncthreads();
    for (int i = 0; i < 10; ++i) {
      int idx = t + i*256;
      int r = idx / 20, g = idx % 20;
      *(us8*)&dst[(size_t)(row0 + r)*DD + g*8] = *(const us8*)&buf[r*PRS + g*8];
    }
  } else {
    #pragma unroll
    for (int nt = 0; nt < 10; ++nt)
      #pragma unroll
      for (int r = 0; r < 4; ++r) {
        buf[(nt*16 + l16)*VTRS + wave*32 + quad*4 + r]      = (f16)acc0[nt][r];
        buf[(nt*16 + l16)*VTRS + wave*32 + 16 + quad*4 + r] = (f16)acc1[nt][r];
      }
    __syncthreads();
    const int b  = row0 / SSY;
    const int y0 = row0 % SSY;
    for (int i = 0; i < 10; ++i) {
      int idx = t + i*256;
      int d = idx / 16, yg = idx % 16;
      *(us8*)&Vtw[((size_t)b*DD + d)*SSY + y0 + yg*8] = *(const us8*)&buf[d*VTRS + yg*8];
    }
  }
}

// ---------------- Flash attention + residual: byte-identical to round 6 ----------------

#define LOAD_CHUNK(yb) { \
  const f16* ksrc = Kw + ((size_t)b*SSY + (yb))*DD; \
  const f16* vsrc = Vtw + (size_t)b*DD*SSY + (yb); \
  _Pragma("unroll") \
  for (int i = 0; i < 5; ++i) { \
    int idx = t + i*256; int r = idx/20, c = idx%20; \
    kreg[i] = *(const us8*)&ksrc[(size_t)r*DD + c*8]; \
  } \
  _Pragma("unroll") \
  for (int i = 0; i < 5; ++i) { \
    int idx = t + i*256; int d = idx>>3, g = idx&7; \
    vreg[i] = *(const us8*)&vsrc[(size_t)d*SSY + g*8]; \
  } \
}

#define STORE_CHUNK() { \
  _Pragma("unroll") \
  for (int i = 0; i < 5; ++i) { \
    int idx = t + i*256; int r = idx/20, c = idx%20; \
    *(us8*)&K_lds[r*RS + c*8] = kreg[i]; \
  } \
  _Pragma("unroll") \
  for (int i = 0; i < 5; ++i) { \
    int idx = t + i*256; int d = idx>>3, g = idx&7; \
    *(us8*)&Vt_lds[d*64 + ((g ^ (d & 7)) << 3)] = vreg[i]; \
  } \
}

__global__ __launch_bounds__(256, 2) void flash_kernel(
    const f16* __restrict__ Qw, const f16* __restrict__ Kw, const f16* __restrict__ Vtw,
    const float* __restrict__ x, float* __restrict__ out)
{
  __shared__ __align__(16) f16 K_lds[64*RS];      // 21504 B (also Q staging)
  __shared__ __align__(16) f16 Vt_lds[160*64];    // 20480 B -> total 41984 B
  const int t = threadIdx.x;
  const int wave = t >> 6;
  const int lane = t & 63;
  const int l31  = lane & 31;
  const int hi   = lane >> 5;
  // 512 blocks = 8 XCDs x 64: each XCD owns 4 complete batches (K/V L2 reuse)
  const int bid  = (blockIdx.x & 7) * 64 + (blockIdx.x >> 3);
  const int b    = bid >> 4;
  const int x0   = (bid & 15) * 128;

  us8 kreg[5], vreg[5];
  LOAD_CHUNK(0);   // overlap chunk-0 HBM latency with Q staging

  // stage Q (128 rows in two 64-row passes through K_lds), hoist B-frags (32 rows/wave)
  f16x8 qfr[10];
  #pragma unroll
  for (int h = 0; h < 2; ++h) {
    if (h) __syncthreads();
    const f16* qsrc = Qw + ((size_t)b*SSX + x0 + h*64)*DD;
    for (int i = 0; i < 5; ++i) {
      int idx = t + i*256;
      int r = idx / 20, c = idx % 20;
      *(us8*)&K_lds[r*RS + c*8] = *(const us8*)&qsrc[(size_t)r*DD + c*8];
    }
    __syncthreads();
    if ((wave >> 1) == h) {
      const int base = (wave & 1)*32;
      #pragma unroll
      for (int s = 0; s < 10; ++s)
        qfr[s] = *(const f16x8*)&K_lds[(base + l31)*RS + s*16 + hi*8];
    }
  }

  f32x16 acc[5];
  #pragma unroll
  for (int i = 0; i < 5; ++i)
    #pragma unroll
    for (int r = 0; r < 16; ++r) acc[i][r] = 0.f;
  float m = -1e30f, l = 0.f;

  for (int yc = 0; yc < SSY/64; ++yc) {
    __syncthreads();          // A: prev compute done reading LDS (and qfr reads at yc=0)
    STORE_CHUNK();
    __syncthreads();          // B: LDS visible
    if (yc < SSY/64 - 1) LOAD_CHUNK((yc+1)*64);   // overlaps compute below

    // S^T = K Q^T : rows = k (C-layout), cols = q = l31
    f32x16 S0, S1;
    #pragma unroll
    for (int r = 0; r < 16; ++r) { S0[r] = 0.f; S1[r] = 0.f; }
    __builtin_amdgcn_s_setprio(1);
    #pragma unroll
    for (int s = 0; s < 10; ++s) {
      f16x8 k0 = *(const f16x8*)&K_lds[l31*RS + s*16 + hi*8];
      f16x8 k1 = *(const f16x8*)&K_lds[(32 + l31)*RS + s*16 + hi*8];
      S0 = mfma32(k0, qfr[s], S0);
      S1 = mfma32(k1, qfr[s], S1);
    }
    __builtin_amdgcn_s_setprio(0);

    // row max (max3-shaped trees)
    float pmax = fmaxf(S0[0], S0[1]);
    #pragma unroll
    for (int r = 2; r < 16; r += 2) pmax = fmaxf(fmaxf(pmax, S0[r]), S0[r+1]);
    #pragma unroll
    for (int r = 0; r < 16; r += 2) pmax = fmaxf(fmaxf(pmax, S1[r]), S1[r+1]);
    pmax = fmaxf(pmax, __shfl_xor(pmax, 32));

    // defer-max: rescale only when max grows by > 8
    if (__any(pmax > m + 8.f)) {
      float n  = fmaxf(m, pmax);
      float sc = exp2f((m - n)*LOG2E);
      m = n; l *= sc;
      #pragma unroll
      for (int r = 0; r < 16; ++r) {
        float scq = __shfl(sc, (r&3) + 8*(r>>2) + 4*hi);
        #pragma unroll
        for (int dt = 0; dt < 5; ++dt) acc[dt][r] *= scq;
      }
    }

    // P = exp(S - m); l accumulates f32 row sum
    float lsum = 0.f;
    #pragma unroll
    for (int r = 0; r < 16; ++r) { S0[r] = exp2f((S0[r] - m)*LOG2E); lsum += S0[r]; }
    #pragma unroll
    for (int r = 0; r < 16; ++r) { S1[r] = exp2f((S1[r] - m)*LOG2E); lsum += S1[r]; }
    lsum += __shfl_xor(lsum, 32);
    l += lsum;

    // pack P -> A-layout in regs (cvt_pkrtz + permlane32_swap), then PV
    #pragma unroll
    for (int c = 0; c < 4; ++c) {
      const int bo = (c & 1)*8;
      float s0 = (c < 2) ? S0[bo+0] : S1[bo+0];
      float s1 = (c < 2) ? S0[bo+1] : S1[bo+1];
      float s2 = (c < 2) ? S0[bo+2] : S1[bo+2];
      float s3 = (c < 2) ? S0[bo+3] : S1[bo+3];
      float s4 = (c < 2) ? S0[bo+4] : S1[bo+4];
      float s5 = (c < 2) ? S0[bo+5] : S1[bo+5];
      float s6 = (c < 2) ? S0[bo+6] : S1[bo+6];
      float s7 = (c < 2) ? S0[bo+7] : S1[bo+7];
      unsigned L0 = pk2rtz(s0, s1), L1 = pk2rtz(s2, s3);
      unsigned H0 = pk2rtz(s4, s5), H1 = pk2rtz(s6, s7);
      i32x2 r02 = __builtin_amdgcn_permlane32_swap((int)L0, (int)H0, false, false);
      i32x2 r13 = __builtin_amdgcn_permlane32_swap((int)L1, (int)H1, false, false);
      union { unsigned u[4]; f16x8 h; } ph;
      ph.u[0] = (unsigned)r02.x; ph.u[1] = (unsigned)r13.x;
      ph.u[2] = (unsigned)r02.y; ph.u[3] = (unsigned)r13.y;
      __builtin_amdgcn_s_setprio(1);
      #pragma unroll
      for (int dt = 0; dt < 5; ++dt) {
        int row = dt*32 + l31;
        f16x8 vf = *(const f16x8*)&Vt_lds[row*64 + (((c*2 + hi) ^ (row & 7)) << 3)];
        acc[dt] = mfma32(ph.h, vf, acc[dt]);
      }
      __builtin_amdgcn_s_setprio(0);
    }
  }

  // epilogue: out = acc/l + x ; acc reg r -> q = (r&3)+8*(r>>2)+4*hi, col d = dt*32+l31
  #pragma unroll
  for (int r = 0; r < 16; ++r) {
    int qr = (r&3) + 8*(r>>2) + 4*hi;
    float rl = 1.f / __shfl(l, qr);
    size_t rowoff = ((size_t)b*SSX + x0 + wave*32 + qr)*DD + l31;
    #pragma unroll
    for (int dt = 0; dt < 5; ++dt) {
      size_t o = rowoff + (size_t)dt*32;
      out[o] = acc[dt][r]*rl + x[o];
    }
  }
}

extern "C" void kernel_launch(void* const* d_in, const int* in_sizes, int n_in,
                              void* d_out, int out_size, void* d_ws, size_t ws_size,
                              hipStream_t stream) {
  const float* x  = (const float*)d_in[0];
  const float* y  = (const float*)d_in[1];
  const float* Wq = (const float*)d_in[2];
  const float* bq = (const float*)d_in[3];
  const float* Wk = (const float*)d_in[4];
  const float* bk = (const float*)d_in[5];
  const float* Wv = (const float*)d_in[6];
  const float* bv = (const float*)d_in[7];

  f16* Qw  = (f16*)d_ws;
  f16* Kw  = Qw + (size_t)M_TOTAL*DD;
  f16* Vtw = Kw + (size_t)M_TOTAL*DD;   // 63 MB for Q/K/Vt
  // Wf (3 x 160x160 f16 = 153600 B) at top of workspace, 256B-aligned
  size_t wf_off = (ws_size - 153600) & ~(size_t)255;
  f16* Wf = (f16*)((char*)d_ws + wf_off);

  wcvt_kernel<<<75, 256, 0, stream>>>(Wq, Wk, Wv, Wf);
  proj_kernel<<<1536, 256, 0, stream>>>(x, y, bq, bk, bv, Wf, Qw, Kw, Vtw);
  flash_kernel<<<512, 256, 0, stream>>>(Qw, Kw, Vtw, x, (float*)d_out);
}

// Round 8
// 281.783 us; speedup vs baseline: 1.0332x; 1.0332x over previous
//
#include <hip/hip_runtime.h>

#define LOG2E 1.44269504088896340736f

typedef _Float16 f16;
typedef __attribute__((ext_vector_type(2))) _Float16 f16x2;
typedef __attribute__((ext_vector_type(2))) __fp16 fp16x2;
typedef __attribute__((ext_vector_type(4))) _Float16 f16x4;
typedef __attribute__((ext_vector_type(8))) _Float16 f16x8;
typedef __attribute__((ext_vector_type(4))) float f32x4;
typedef __attribute__((ext_vector_type(16))) float f32x16;
typedef __attribute__((ext_vector_type(8))) unsigned short us8;
typedef __attribute__((ext_vector_type(2))) int i32x2;

#define BB 32
#define SSX 2048
#define SSY 2048
#define DD 160
#define M_TOTAL (BB*SSX)   // 65536

#define PRS 168    // proj LDS row stride (f16)
#define VTRS 136   // proj V^T store buffer stride
#define RS 168     // flash K/Q LDS stride (pad-8: const-offset ds_reads)

__device__ __forceinline__ f32x4 mfma16(f16x8 a, f16x8 b, f32x4 c) {
  return __builtin_amdgcn_mfma_f32_16x16x32_f16(a, b, c, 0, 0, 0);
}

__device__ __forceinline__ f32x16 mfma32(f16x8 a, f16x8 b, f32x16 c) {
  return __builtin_amdgcn_mfma_f32_32x32x16_f16(a, b, c, 0, 0, 0);
}

// RTZ pack of two f32 -> u32 of 2 f16 (low = a). P in [0,1]: RTZ error ~2^-12, negligible.
__device__ __forceinline__ unsigned pk2rtz(float a, float b) {
  union { fp16x2 h; unsigned u; } x;
  x.h = __builtin_amdgcn_cvt_pkrtz(a, b);
  return x.u;
}

// ---- W pre-conversion: fp32 -> f16 once ----
__global__ __launch_bounds__(256) void wcvt_kernel(
    const float* __restrict__ Wq, const float* __restrict__ Wk, const float* __restrict__ Wv,
    f16* __restrict__ Wf)
{
  int idx = blockIdx.x*256 + threadIdx.x;   // 75 blocks * 256 = 19200 float4
  int which = idx / 6400;                   // uniform per block (6400 % 256 == 0)
  int off   = idx % 6400;
  const float* src = (which == 0) ? Wq : (which == 1 ? Wk : Wv);
  float4 v = *(const float4*)&src[off*4];
  f16x4 h = { (f16)v.x, (f16)v.y, (f16)v.z, (f16)v.w };
  *(f16x4*)&Wf[which*25600 + off*4] = h;
}

// ---- Projection v5: A-side DIRECT to registers (stream-once, no reuse);
// B-side (W) staged f16 into LDS (keeps the 50 B-frag reads per lane OFF the
// L2-latency path that poisoned v4). One barrier before MFMA, one before
// epilogue buf reuse. 1536 blocks, 3/CU.
__global__ __launch_bounds__(256, 3) void proj_kernel(
    const float* __restrict__ x, const float* __restrict__ y,
    const float* __restrict__ bq, const float* __restrict__ bk, const float* __restrict__ bv,
    const f16* __restrict__ Wf,
    f16* __restrict__ Qw, f16* __restrict__ Kw, f16* __restrict__ Vtw)
{
  __shared__ __align__(16) f16 buf[160*PRS];   // 53760 B -> 3 blocks/CU
  const int t = threadIdx.x;
  const int wave = t >> 6;
  const int lane = t & 63;
  const int quad = lane >> 4;
  const int l16  = lane & 15;
  // 1536 blocks = 8 XCDs x 192: contiguous logical range per XCD; Q,K,V adjacent share x/y tiles in L2
  const int bid  = (blockIdx.x & 7) * 192 + (blockIdx.x >> 3);
  const int kind = bid % 3;          // 0=Q, 1=K, 2=V
  const int tile = bid / 3;
  const int row0 = tile * 128;
  const float* src  = (kind == 0) ? x  : y;
  const f16*   W    = Wf + kind*25600;
  const float* bias = (kind == 0) ? bq : (kind == 1 ? bk : bv);

  // stage W (160x160 f16) into LDS: 3200 us8 over 256 threads
  #pragma unroll
  for (int i = 0; i < 12; ++i) {
    int idx = t + i*256;
    int r = idx / 20, g = idx % 20;
    *(us8*)&buf[r*PRS + g*8] = *(const us8*)&W[idx*8];
  }
  if (t < 128) {
    int idx = t + 3072;
    int r = idx / 20, g = idx % 20;
    *(us8*)&buf[r*PRS + g*8] = *(const us8*)&W[idx*8];
  }

  // A-fragments: global f32 -> f16 registers (overlaps W staging)
  f16x8 afr0[5], afr1[5];
  {
    const float* r0p = src + (size_t)(row0 + wave*32 + l16)*DD;
    const float* r1p = r0p + 16*DD;
    #pragma unroll
    for (int ks = 0; ks < 5; ++ks) {
      float4 a = *(const float4*)&r0p[ks*32 + quad*8];
      float4 b = *(const float4*)&r0p[ks*32 + quad*8 + 4];
      afr0[ks] = (f16x8){(f16)a.x,(f16)a.y,(f16)a.z,(f16)a.w,
                         (f16)b.x,(f16)b.y,(f16)b.z,(f16)b.w};
      float4 c = *(const float4*)&r1p[ks*32 + quad*8];
      float4 d = *(const float4*)&r1p[ks*32 + quad*8 + 4];
      afr1[ks] = (f16x8){(f16)c.x,(f16)c.y,(f16)c.z,(f16)c.w,
                         (f16)d.x,(f16)d.y,(f16)d.z,(f16)d.w};
    }
  }
  __syncthreads();   // W staged

  f32x4 acc0[10], acc1[10];
  #pragma unroll
  for (int nt = 0; nt < 10; ++nt) {
    float bs = bias[nt*16 + l16];
    acc0[nt] = (f32x4){bs,bs,bs,bs};
    acc1[nt] = (f32x4){bs,bs,bs,bs};
    #pragma unroll
    for (int ks = 0; ks < 5; ++ks) {
      f16x8 bfr = *(const f16x8*)&buf[(nt*16 + l16)*PRS + ks*32 + quad*8];
      acc0[nt] = mfma16(afr0[ks], bfr, acc0[nt]);
      acc1[nt] = mfma16(afr1[ks], bfr, acc1[nt]);
    }
  }
  __syncthreads();   // B-reads done before buf reuse

  if (kind < 2) {
    f16* dst = (kind == 0) ? Qw : Kw;
    #pragma unroll
    for (int nt = 0; nt < 10; ++nt)
      #pragma unroll
      for (int r = 0; r < 4; ++r) {
        buf[(wave*32 + quad*4 + r)*PRS + nt*16 + l16]      = (f16)acc0[nt][r];
        buf[(wave*32 + 16 + quad*4 + r)*PRS + nt*16 + l16] = (f16)acc1[nt][r];
      }
    __syncthreads();
    for (int i = 0; i < 10; ++i) {
      int idx = t + i*256;
      int r = idx / 20, g = idx % 20;
      *(us8*)&dst[(size_t)(row0 + r)*DD + g*8] = *(const us8*)&buf[r*PRS + g*8];
    }
  } else {
    #pragma unroll
    for (int nt = 0; nt < 10; ++nt)
      #pragma unroll
      for (int r = 0; r < 4; ++r) {
        buf[(nt*16 + l16)*VTRS + wave*32 + quad*4 + r]      = (f16)acc0[nt][r];
        buf[(nt*16 + l16)*VTRS + wave*32 + 16 + quad*4 + r] = (f16)acc1[nt][r];
      }
    __syncthreads();
    const int b  = row0 / SSY;
    const int y0 = row0 % SSY;
    for (int i = 0; i < 10; ++i) {
      int idx = t + i*256;
      int d = idx / 16, yg = idx % 16;
      *(us8*)&Vtw[((size_t)b*DD + d)*SSY + y0 + yg*8] = *(const us8*)&buf[d*VTRS + yg*8];
    }
  }
}

// ---------------- Flash attention + residual: byte-identical to round 6/7 ----------------

#define LOAD_CHUNK(yb) { \
  const f16* ksrc = Kw + ((size_t)b*SSY + (yb))*DD; \
  const f16* vsrc = Vtw + (size_t)b*DD*SSY + (yb); \
  _Pragma("unroll") \
  for (int i = 0; i < 5; ++i) { \
    int idx = t + i*256; int r = idx/20, c = idx%20; \
    kreg[i] = *(const us8*)&ksrc[(size_t)r*DD + c*8]; \
  } \
  _Pragma("unroll") \
  for (int i = 0; i < 5; ++i) { \
    int idx = t + i*256; int d = idx>>3, g = idx&7; \
    vreg[i] = *(const us8*)&vsrc[(size_t)d*SSY + g*8]; \
  } \
}

#define STORE_CHUNK() { \
  _Pragma("unroll") \
  for (int i = 0; i < 5; ++i) { \
    int idx = t + i*256; int r = idx/20, c = idx%20; \
    *(us8*)&K_lds[r*RS + c*8] = kreg[i]; \
  } \
  _Pragma("unroll") \
  for (int i = 0; i < 5; ++i) { \
    int idx = t + i*256; int d = idx>>3, g = idx&7; \
    *(us8*)&Vt_lds[d*64 + ((g ^ (d & 7)) << 3)] = vreg[i]; \
  } \
}

__global__ __launch_bounds__(256, 2) void flash_kernel(
    const f16* __restrict__ Qw, const f16* __restrict__ Kw, const f16* __restrict__ Vtw,
    const float* __restrict__ x, float* __restrict__ out)
{
  __shared__ __align__(16) f16 K_lds[64*RS];      // 21504 B (also Q staging)
  __shared__ __align__(16) f16 Vt_lds[160*64];    // 20480 B -> total 41984 B
  const int t = threadIdx.x;
  const int wave = t >> 6;
  const int lane = t & 63;
  const int l31  = lane & 31;
  const int hi   = lane >> 5;
  // 512 blocks = 8 XCDs x 64: each XCD owns 4 complete batches (K/V L2 reuse)
  const int bid  = (blockIdx.x & 7) * 64 + (blockIdx.x >> 3);
  const int b    = bid >> 4;
  const int x0   = (bid & 15) * 128;

  us8 kreg[5], vreg[5];
  LOAD_CHUNK(0);   // overlap chunk-0 HBM latency with Q staging

  // stage Q (128 rows in two 64-row passes through K_lds), hoist B-frags (32 rows/wave)
  f16x8 qfr[10];
  #pragma unroll
  for (int h = 0; h < 2; ++h) {
    if (h) __syncthreads();
    const f16* qsrc = Qw + ((size_t)b*SSX + x0 + h*64)*DD;
    for (int i = 0; i < 5; ++i) {
      int idx = t + i*256;
      int r = idx / 20, c = idx % 20;
      *(us8*)&K_lds[r*RS + c*8] = *(const us8*)&qsrc[(size_t)r*DD + c*8];
    }
    __syncthreads();
    if ((wave >> 1) == h) {
      const int base = (wave & 1)*32;
      #pragma unroll
      for (int s = 0; s < 10; ++s)
        qfr[s] = *(const f16x8*)&K_lds[(base + l31)*RS + s*16 + hi*8];
    }
  }

  f32x16 acc[5];
  #pragma unroll
  for (int i = 0; i < 5; ++i)
    #pragma unroll
    for (int r = 0; r < 16; ++r) acc[i][r] = 0.f;
  float m = -1e30f, l = 0.f;

  for (int yc = 0; yc < SSY/64; ++yc) {
    __syncthreads();          // A: prev compute done reading LDS (and qfr reads at yc=0)
    STORE_CHUNK();
    __syncthreads();          // B: LDS visible
    if (yc < SSY/64 - 1) LOAD_CHUNK((yc+1)*64);   // overlaps compute below

    // S^T = K Q^T : rows = k (C-layout), cols = q = l31
    f32x16 S0, S1;
    #pragma unroll
    for (int r = 0; r < 16; ++r) { S0[r] = 0.f; S1[r] = 0.f; }
    __builtin_amdgcn_s_setprio(1);
    #pragma unroll
    for (int s = 0; s < 10; ++s) {
      f16x8 k0 = *(const f16x8*)&K_lds[l31*RS + s*16 + hi*8];
      f16x8 k1 = *(const f16x8*)&K_lds[(32 + l31)*RS + s*16 + hi*8];
      S0 = mfma32(k0, qfr[s], S0);
      S1 = mfma32(k1, qfr[s], S1);
    }
    __builtin_amdgcn_s_setprio(0);

    // row max (max3-shaped trees)
    float pmax = fmaxf(S0[0], S0[1]);
    #pragma unroll
    for (int r = 2; r < 16; r += 2) pmax = fmaxf(fmaxf(pmax, S0[r]), S0[r+1]);
    #pragma unroll
    for (int r = 0; r < 16; r += 2) pmax = fmaxf(fmaxf(pmax, S1[r]), S1[r+1]);
    pmax = fmaxf(pmax, __shfl_xor(pmax, 32));

    // defer-max: rescale only when max grows by > 8
    if (__any(pmax > m + 8.f)) {
      float n  = fmaxf(m, pmax);
      float sc = exp2f((m - n)*LOG2E);
      m = n; l *= sc;
      #pragma unroll
      for (int r = 0; r < 16; ++r) {
        float scq = __shfl(sc, (r&3) + 8*(r>>2) + 4*hi);
        #pragma unroll
        for (int dt = 0; dt < 5; ++dt) acc[dt][r] *= scq;
      }
    }

    // P = exp(S - m); l accumulates f32 row sum
    float lsum = 0.f;
    #pragma unroll
    for (int r = 0; r < 16; ++r) { S0[r] = exp2f((S0[r] - m)*LOG2E); lsum += S0[r]; }
    #pragma unroll
    for (int r = 0; r < 16; ++r) { S1[r] = exp2f((S1[r] - m)*LOG2E); lsum += S1[r]; }
    lsum += __shfl_xor(lsum, 32);
    l += lsum;

    // pack P -> A-layout in regs (cvt_pkrtz + permlane32_swap), then PV
    #pragma unroll
    for (int c = 0; c < 4; ++c) {
      const int bo = (c & 1)*8;
      float s0 = (c < 2) ? S0[bo+0] : S1[bo+0];
      float s1 = (c < 2) ? S0[bo+1] : S1[bo+1];
      float s2 = (c < 2) ? S0[bo+2] : S1[bo+2];
      float s3 = (c < 2) ? S0[bo+3] : S1[bo+3];
      float s4 = (c < 2) ? S0[bo+4] : S1[bo+4];
      float s5 = (c < 2) ? S0[bo+5] : S1[bo+5];
      float s6 = (c < 2) ? S0[bo+6] : S1[bo+6];
      float s7 = (c < 2) ? S0[bo+7] : S1[bo+7];
      unsigned L0 = pk2rtz(s0, s1), L1 = pk2rtz(s2, s3);
      unsigned H0 = pk2rtz(s4, s5), H1 = pk2rtz(s6, s7);
      i32x2 r02 = __builtin_amdgcn_permlane32_swap((int)L0, (int)H0, false, false);
      i32x2 r13 = __builtin_amdgcn_permlane32_swap((int)L1, (int)H1, false, false);
      union { unsigned u[4]; f16x8 h; } ph;
      ph.u[0] = (unsigned)r02.x; ph.u[1] = (unsigned)r13.x;
      ph.u[2] = (unsigned)r02.y; ph.u[3] = (unsigned)r13.y;
      __builtin_amdgcn_s_setprio(1);
      #pragma unroll
      for (int dt = 0; dt < 5; ++dt) {
        int row = dt*32 + l31;
        f16x8 vf = *(const f16x8*)&Vt_lds[row*64 + (((c*2 + hi) ^ (row & 7)) << 3)];
        acc[dt] = mfma32(ph.h, vf, acc[dt]);
      }
      __builtin_amdgcn_s_setprio(0);
    }
  }

  // epilogue: out = acc/l + x ; acc reg r -> q = (r&3)+8*(r>>2)+4*hi, col d = dt*32+l31
  #pragma unroll
  for (int r = 0; r < 16; ++r) {
    int qr = (r&3) + 8*(r>>2) + 4*hi;
    float rl = 1.f / __shfl(l, qr);
    size_t rowoff = ((size_t)b*SSX + x0 + wave*32 + qr)*DD + l31;
    #pragma unroll
    for (int dt = 0; dt < 5; ++dt) {
      size_t o = rowoff + (size_t)dt*32;
      out[o] = acc[dt][r]*rl + x[o];
    }
  }
}

extern "C" void kernel_launch(void* const* d_in, const int* in_sizes, int n_in,
                              void* d_out, int out_size, void* d_ws, size_t ws_size,
                              hipStream_t stream) {
  const float* x  = (const float*)d_in[0];
  const float* y  = (const float*)d_in[1];
  const float* Wq = (const float*)d_in[2];
  const float* bq = (const float*)d_in[3];
  const float* Wk = (const float*)d_in[4];
  const float* bk = (const float*)d_in[5];
  const float* Wv = (const float*)d_in[6];
  const float* bv = (const float*)d_in[7];

  f16* Qw  = (f16*)d_ws;
  f16* Kw  = Qw + (size_t)M_TOTAL*DD;
  f16* Vtw = Kw + (size_t)M_TOTAL*DD;   // 63 MB for Q/K/Vt
  // Wf (3 x 160x160 f16 = 153600 B) at top of workspace, 256B-aligned
  size_t wf_off = (ws_size - 153600) & ~(size_t)255;
  f16* Wf = (f16*)((char*)d_ws + wf_off);

  wcvt_kernel<<<75, 256, 0, stream>>>(Wq, Wk, Wv, Wf);
  proj_kernel<<<1536, 256, 0, stream>>>(x, y, bq, bk, bv, Wf, Qw, Kw, Vtw);
  flash_kernel<<<512, 256, 0, stream>>>(Qw, Kw, Vtw, x, (float*)d_out);
}

// Round 9
// 272.468 us; speedup vs baseline: 1.0685x; 1.0342x over previous
//
#include <hip/hip_runtime.h>

#define LOG2E 1.44269504088896340736f

typedef _Float16 f16;
typedef __attribute__((ext_vector_type(2))) _Float16 f16x2;
typedef __attribute__((ext_vector_type(2))) __fp16 fp16x2;
typedef __attribute__((ext_vector_type(4))) _Float16 f16x4;
typedef __attribute__((ext_vector_type(8))) _Float16 f16x8;
typedef __attribute__((ext_vector_type(4))) float f32x4;
typedef __attribute__((ext_vector_type(16))) float f32x16;
typedef __attribute__((ext_vector_type(8))) unsigned short us8;
typedef __attribute__((ext_vector_type(2))) int i32x2;

#define BB 32
#define SSX 2048
#define SSY 2048
#define DD 160
#define M_TOTAL (BB*SSX)   // 65536

#define PRS 168    // proj LDS row stride (f16)
#define VTRS 136   // proj V^T store buffer stride
#define RS 168     // flash K/Q LDS stride (pad-8: const-offset ds_reads, 4-way max)
#define KVB 32     // flash y-chunk
#define VRS 40     // flash V row stride (pad-40: granule 5*row%8, 4-way max, const offsets)

__device__ __forceinline__ f32x4 mfma16(f16x8 a, f16x8 b, f32x4 c) {
  return __builtin_amdgcn_mfma_f32_16x16x32_f16(a, b, c, 0, 0, 0);
}

__device__ __forceinline__ f32x16 mfma32(f16x8 a, f16x8 b, f32x16 c) {
  return __builtin_amdgcn_mfma_f32_32x32x16_f16(a, b, c, 0, 0, 0);
}

// RTZ pack of two f32 -> u32 of 2 f16 (low = a). P in [0,1]: RTZ error ~2^-12, negligible.
__device__ __forceinline__ unsigned pk2rtz(float a, float b) {
  union { fp16x2 h; unsigned u; } x;
  x.h = __builtin_amdgcn_cvt_pkrtz(a, b);
  return x.u;
}

// ---- W pre-conversion: fp32 -> f16 once ----
__global__ __launch_bounds__(256) void wcvt_kernel(
    const float* __restrict__ Wq, const float* __restrict__ Wk, const float* __restrict__ Wv,
    f16* __restrict__ Wf)
{
  int idx = blockIdx.x*256 + threadIdx.x;   // 75 blocks * 256 = 19200 float4
  int which = idx / 6400;                   // uniform per block (6400 % 256 == 0)
  int off   = idx % 6400;
  const float* src = (which == 0) ? Wq : (which == 1 ? Wk : Wv);
  float4 v = *(const float4*)&src[off*4];
  f16x4 h = { (f16)v.x, (f16)v.y, (f16)v.z, (f16)v.w };
  *(f16x4*)&Wf[which*25600 + off*4] = h;
}

// ---- Projection v5 (byte-identical to round 8) ----
__global__ __launch_bounds__(256, 3) void proj_kernel(
    const float* __restrict__ x, const float* __restrict__ y,
    const float* __restrict__ bq, const float* __restrict__ bk, const float* __restrict__ bv,
    const f16* __restrict__ Wf,
    f16* __restrict__ Qw, f16* __restrict__ Kw, f16* __restrict__ Vtw)
{
  __shared__ __align__(16) f16 buf[160*PRS];   // 53760 B -> 3 blocks/CU
  const int t = threadIdx.x;
  const int wave = t >> 6;
  const int lane = t & 63;
  const int quad = lane >> 4;
  const int l16  = lane & 15;
  const int bid  = (blockIdx.x & 7) * 192 + (blockIdx.x >> 3);
  const int kind = bid % 3;          // 0=Q, 1=K, 2=V
  const int tile = bid / 3;
  const int row0 = tile * 128;
  const float* src  = (kind == 0) ? x  : y;
  const f16*   W    = Wf + kind*25600;
  const float* bias = (kind == 0) ? bq : (kind == 1 ? bk : bv);

  // stage W (160x160 f16) into LDS: 3200 us8 over 256 threads
  #pragma unroll
  for (int i = 0; i < 12; ++i) {
    int idx = t + i*256;
    int r = idx / 20, g = idx % 20;
    *(us8*)&buf[r*PRS + g*8] = *(const us8*)&W[idx*8];
  }
  if (t < 128) {
    int idx = t + 3072;
    int r = idx / 20, g = idx % 20;
    *(us8*)&buf[r*PRS + g*8] = *(const us8*)&W[idx*8];
  }

  // A-fragments: global f32 -> f16 registers (overlaps W staging)
  f16x8 afr0[5], afr1[5];
  {
    const float* r0p = src + (size_t)(row0 + wave*32 + l16)*DD;
    const float* r1p = r0p + 16*DD;
    #pragma unroll
    for (int ks = 0; ks < 5; ++ks) {
      float4 a = *(const float4*)&r0p[ks*32 + quad*8];
      float4 b = *(const float4*)&r0p[ks*32 + quad*8 + 4];
      afr0[ks] = (f16x8){(f16)a.x,(f16)a.y,(f16)a.z,(f16)a.w,
                         (f16)b.x,(f16)b.y,(f16)b.z,(f16)b.w};
      float4 c = *(const float4*)&r1p[ks*32 + quad*8];
      float4 d = *(const float4*)&r1p[ks*32 + quad*8 + 4];
      afr1[ks] = (f16x8){(f16)c.x,(f16)c.y,(f16)c.z,(f16)c.w,
                         (f16)d.x,(f16)d.y,(f16)d.z,(f16)d.w};
    }
  }
  __syncthreads();   // W staged

  f32x4 acc0[10], acc1[10];
  #pragma unroll
  for (int nt = 0; nt < 10; ++nt) {
    float bs = bias[nt*16 + l16];
    acc0[nt] = (f32x4){bs,bs,bs,bs};
    acc1[nt] = (f32x4){bs,bs,bs,bs};
    #pragma unroll
    for (int ks = 0; ks < 5; ++ks) {
      f16x8 bfr = *(const f16x8*)&buf[(nt*16 + l16)*PRS + ks*32 + quad*8];
      acc0[nt] = mfma16(afr0[ks], bfr, acc0[nt]);
      acc1[nt] = mfma16(afr1[ks], bfr, acc1[nt]);
    }
  }
  __syncthreads();   // B-reads done before buf reuse

  if (kind < 2) {
    f16* dst = (kind == 0) ? Qw : Kw;
    #pragma unroll
    for (int nt = 0; nt < 10; ++nt)
      #pragma unroll
      for (int r = 0; r < 4; ++r) {
        buf[(wave*32 + quad*4 + r)*PRS + nt*16 + l16]      = (f16)acc0[nt][r];
        buf[(wave*32 + 16 + quad*4 + r)*PRS + nt*16 + l16] = (f16)acc1[nt][r];
      }
    __syncthreads();
    for (int i = 0; i < 10; ++i) {
      int idx = t + i*256;
      int r = idx / 20, g = idx % 20;
      *(us8*)&dst[(size_t)(row0 + r)*DD + g*8] = *(const us8*)&buf[r*PRS + g*8];
    }
  } else {
    #pragma unroll
    for (int nt = 0; nt < 10; ++nt)
      #pragma unroll
      for (int r = 0; r < 4; ++r) {
        buf[(nt*16 + l16)*VTRS + wave*32 + quad*4 + r]      = (f16)acc0[nt][r];
        buf[(nt*16 + l16)*VTRS + wave*32 + 16 + quad*4 + r] = (f16)acc1[nt][r];
      }
    __syncthreads();
    const int b  = row0 / SSY;
    const int y0 = row0 % SSY;
    for (int i = 0; i < 10; ++i) {
      int idx = t + i*256;
      int d = idx / 16, yg = idx % 16;
      *(us8*)&Vtw[((size_t)b*DD + d)*SSY + y0 + yg*8] = *(const us8*)&buf[d*VTRS + yg*8];
    }
  }
}

// ---------------- Flash attention + residual v2 ----------------
// 2 waves x 32 q-rows = 64 q-rows/block, KVB=32, grid 1024 -> 4 blocks/CU
// (old grid 512 capped occupancy at 2 blocks/CU; per-y-element math identical).
// K pad-168, V pad-40: both 4-way max, all-const ds offsets, no swizzle.

#define LOAD_CHUNK(yb) { \
  const f16* ksrc = Kw + ((size_t)b*SSY + (yb))*DD; \
  const f16* vsrc = Vtw + (size_t)b*DD*SSY + (yb); \
  _Pragma("unroll") \
  for (int i = 0; i < 5; ++i) { \
    int idx = t + i*128; int r = idx/20, c = idx%20; \
    kreg[i] = *(const us8*)&ksrc[(size_t)r*DD + c*8]; \
  } \
  _Pragma("unroll") \
  for (int i = 0; i < 5; ++i) { \
    int idx = t + i*128; int d = idx>>2, g = idx&3; \
    vreg[i] = *(const us8*)&vsrc[(size_t)d*SSY + g*8]; \
  } \
}

#define STORE_CHUNK() { \
  _Pragma("unroll") \
  for (int i = 0; i < 5; ++i) { \
    int idx = t + i*128; int r = idx/20, c = idx%20; \
    *(us8*)&K_lds[r*RS + c*8] = kreg[i]; \
  } \
  _Pragma("unroll") \
  for (int i = 0; i < 5; ++i) { \
    int idx = t + i*128; int d = idx>>2, g = idx&3; \
    *(us8*)&Vt_lds[d*VRS + g*8] = vreg[i]; \
  } \
}

__global__ __launch_bounds__(128, 2) void flash_kernel(
    const f16* __restrict__ Qw, const f16* __restrict__ Kw, const f16* __restrict__ Vtw,
    const float* __restrict__ x, float* __restrict__ out)
{
  __shared__ __align__(16) f16 K_lds[KVB*RS];     // 10752 B (also Q staging, 32 rows/pass)
  __shared__ __align__(16) f16 Vt_lds[160*VRS];   // 12800 B -> total 23552 B, 4 blocks/CU
  const int t = threadIdx.x;      // 0..127
  const int wave = t >> 6;        // 0..1
  const int lane = t & 63;
  const int l31  = lane & 31;
  const int hi   = lane >> 5;
  // 1024 blocks = 8 XCDs x 128: each XCD owns 4 complete batches (K/V L2 reuse)
  const int bid  = (blockIdx.x & 7) * 128 + (blockIdx.x >> 3);
  const int b    = bid >> 5;
  const int x0   = (bid & 31) * 64;

  us8 kreg[5], vreg[5];
  LOAD_CHUNK(0);   // overlap chunk-0 HBM latency with Q staging

  // stage Q (64 rows in two 32-row passes through K_lds), hoist B-frags (32 rows/wave)
  f16x8 qfr[10];
  #pragma unroll
  for (int h = 0; h < 2; ++h) {
    if (h) __syncthreads();
    const f16* qsrc = Qw + ((size_t)b*SSX + x0 + h*32)*DD;
    for (int i = 0; i < 5; ++i) {
      int idx = t + i*128;
      int r = idx / 20, c = idx % 20;
      *(us8*)&K_lds[r*RS + c*8] = *(const us8*)&qsrc[(size_t)r*DD + c*8];
    }
    __syncthreads();
    if (wave == h) {
      #pragma unroll
      for (int s = 0; s < 10; ++s)
        qfr[s] = *(const f16x8*)&K_lds[l31*RS + s*16 + hi*8];
    }
  }

  f32x16 acc[5];
  #pragma unroll
  for (int i = 0; i < 5; ++i)
    #pragma unroll
    for (int r = 0; r < 16; ++r) acc[i][r] = 0.f;
  float m = -1e30f, l = 0.f;

  for (int yc = 0; yc < SSY/KVB; ++yc) {
    __syncthreads();          // A: prev compute done reading LDS (and qfr reads at yc=0)
    STORE_CHUNK();
    __syncthreads();          // B: LDS visible
    if (yc < SSY/KVB - 1) LOAD_CHUNK((yc+1)*KVB);   // overlaps compute below

    // S^T = K Q^T : rows = k (C-layout), cols = q = l31
    f32x16 S0;
    #pragma unroll
    for (int r = 0; r < 16; ++r) S0[r] = 0.f;
    __builtin_amdgcn_s_setprio(1);
    #pragma unroll
    for (int s = 0; s < 10; ++s) {
      f16x8 k0 = *(const f16x8*)&K_lds[l31*RS + s*16 + hi*8];
      S0 = mfma32(k0, qfr[s], S0);
    }
    __builtin_amdgcn_s_setprio(0);

    // row max (16 in-lane + cross-half)
    float pmax = fmaxf(S0[0], S0[1]);
    #pragma unroll
    for (int r = 2; r < 16; r += 2) pmax = fmaxf(fmaxf(pmax, S0[r]), S0[r+1]);
    pmax = fmaxf(pmax, __shfl_xor(pmax, 32));

    // defer-max: rescale only when max grows by > 8
    if (__any(pmax > m + 8.f)) {
      float n  = fmaxf(m, pmax);
      float sc = exp2f((m - n)*LOG2E);
      m = n; l *= sc;
      #pragma unroll
      for (int r = 0; r < 16; ++r) {
        float scq = __shfl(sc, (r&3) + 8*(r>>2) + 4*hi);
        #pragma unroll
        for (int dt = 0; dt < 5; ++dt) acc[dt][r] *= scq;
      }
    }

    // P = exp(S - m); l accumulates f32 row sum
    float lsum = 0.f;
    #pragma unroll
    for (int r = 0; r < 16; ++r) { S0[r] = exp2f((S0[r] - m)*LOG2E); lsum += S0[r]; }
    lsum += __shfl_xor(lsum, 32);
    l += lsum;

    // pack P -> A-layout in regs (cvt_pkrtz + permlane32_swap), then PV
    #pragma unroll
    for (int c = 0; c < 2; ++c) {
      const int bo = c*8;
      unsigned L0 = pk2rtz(S0[bo+0], S0[bo+1]), L1 = pk2rtz(S0[bo+2], S0[bo+3]);
      unsigned H0 = pk2rtz(S0[bo+4], S0[bo+5]), H1 = pk2rtz(S0[bo+6], S0[bo+7]);
      i32x2 r02 = __builtin_amdgcn_permlane32_swap((int)L0, (int)H0, false, false);
      i32x2 r13 = __builtin_amdgcn_permlane32_swap((int)L1, (int)H1, false, false);
      union { unsigned u[4]; f16x8 h; } ph;
      ph.u[0] = (unsigned)r02.x; ph.u[1] = (unsigned)r13.x;
      ph.u[2] = (unsigned)r02.y; ph.u[3] = (unsigned)r13.y;
      __builtin_amdgcn_s_setprio(1);
      #pragma unroll
      for (int dt = 0; dt < 5; ++dt) {
        int row = dt*32 + l31;
        f16x8 vf = *(const f16x8*)&Vt_lds[row*VRS + (c*2 + hi)*8];
        acc[dt] = mfma32(ph.h, vf, acc[dt]);
      }
      __builtin_amdgcn_s_setprio(0);
    }
  }

  // epilogue: out = acc/l + x ; acc reg r -> q = (r&3)+8*(r>>2)+4*hi, col d = dt*32+l31
  #pragma unroll
  for (int r = 0; r < 16; ++r) {
    int qr = (r&3) + 8*(r>>2) + 4*hi;
    float rl = 1.f / __shfl(l, qr);
    size_t rowoff = ((size_t)b*SSX + x0 + wave*32 + qr)*DD + l31;
    #pragma unroll
    for (int dt = 0; dt < 5; ++dt) {
      size_t o = rowoff + (size_t)dt*32;
      out[o] = acc[dt][r]*rl + x[o];
    }
  }
}

extern "C" void kernel_launch(void* const* d_in, const int* in_sizes, int n_in,
                              void* d_out, int out_size, void* d_ws, size_t ws_size,
                              hipStream_t stream) {
  const float* x  = (const float*)d_in[0];
  const float* y  = (const float*)d_in[1];
  const float* Wq = (const float*)d_in[2];
  const float* bq = (const float*)d_in[3];
  const float* Wk = (const float*)d_in[4];
  const float* bk = (const float*)d_in[5];
  const float* Wv = (const float*)d_in[6];
  const float* bv = (const float*)d_in[7];

  f16* Qw  = (f16*)d_ws;
  f16* Kw  = Qw + (size_t)M_TOTAL*DD;
  f16* Vtw = Kw + (size_t)M_TOTAL*DD;   // 63 MB for Q/K/Vt
  // Wf (3 x 160x160 f16 = 153600 B) at top of workspace, 256B-aligned
  size_t wf_off = (ws_size - 153600) & ~(size_t)255;
  f16* Wf = (f16*)((char*)d_ws + wf_off);

  wcvt_kernel<<<75, 256, 0, stream>>>(Wq, Wk, Wv, Wf);
  proj_kernel<<<1536, 256, 0, stream>>>(x, y, bq, bk, bv, Wf, Qw, Kw, Vtw);
  flash_kernel<<<1024, 128, 0, stream>>>(Qw, Kw, Vtw, x, (float*)d_out);
}